// Round 8
// baseline (84.031 us; speedup 1.0000x reference)
//
#include <hip/hip_runtime.h>
#include <hip/hip_bf16.h>

#define K_SEL 16
#define NCAND 20

typedef __attribute__((ext_vector_type(8))) short short8;
typedef __attribute__((ext_vector_type(4))) float f32x4;

__device__ __forceinline__ short f2bf_bits(float v) {
    union { __hip_bfloat16 b; short s; } u;
    u.b = __float2bfloat16(v);                    // RNE HW convert
    return u.s;
}
__device__ __forceinline__ float bf2f_bits(short h) {
    return __uint_as_float(((unsigned)(unsigned short)h) << 16);
}

// ---------------------------------------------------------------------------
// pack_kernel: all 6 weight matrices -> split-bf16 hi/lo planes in B-fragment
// order: idx = ((ks*N + n)*4 + kb)*8 + i  <->  W[ks*32+kb*8+i][n].
// ---------------------------------------------------------------------------
__global__ __launch_bounds__(256) void pack_kernel(
    const float* __restrict__ s0w, const float* __restrict__ s1w,
    const float* __restrict__ sow, const float* __restrict__ o0w,
    const float* __restrict__ o1w, const float* __restrict__ oow,
    short* __restrict__ wpack)
{
    int t = blockIdx.x * 256 + threadIdx.x;
    if (t >= 69632) return;
    int l, base;
    if      (t <  8192) { l = 0; base = 0;     }
    else if (t < 24576) { l = 1; base = 8192;  }
    else if (t < 32768) { l = 2; base = 24576; }
    else if (t < 45056) { l = 3; base = 32768; }
    else if (t < 61440) { l = 4; base = 45056; }
    else                { l = 5; base = 61440; }

    const float* W = (l == 0) ? s0w : (l == 1) ? s1w : (l == 2) ? sow
                   : (l == 3) ? o0w : (l == 4) ? o1w : oow;
    int N    = (l == 2 || l == 5) ? 64 : 128;
    int Kr   = (l == 0) ? 48 : (l == 3) ? 96 : 128;
    int woff = (l == 0) ? 0 : (l == 1) ? 16384 : (l == 2) ? 49152
             : (l == 3) ? 65536 : (l == 4) ? 90112 : 122880;
    int sz   = (l == 2 || l == 5) ? 8192 : (l == 3) ? 12288 : (l == 0) ? 8192 : 16384;

    int e = t - base;
    int i = e & 7, kb = (e >> 3) & 3, rem = e >> 5;
    int n = rem % N, ks = rem / N;
    int k = ks * 32 + kb * 8 + i;
    float v = (k < Kr) ? W[k * N + n] : 0.0f;
    short hi = f2bf_bits(v);
    float lo = v - bf2f_bits(hi);
    wpack[woff + e]      = hi;
    wpack[woff + sz + e] = f2bf_bits(lo);
}

// ---------------------------------------------------------------------------
// mfma_layer32: one FFN layer for a 32-pixel tile; wave owns M-tile mt (0..1)
// and N-tile nt (16 cols).  Split-bf16: hi*hi + hi*lo + lo*hi.
// LDS activation layout: row p (512 B), 16B granule XOR ^((p&7)<<4).
// C/D mapping: col = lane&15, row = (lane>>4)*4 + r   [m89/m91 verified]
// ---------------------------------------------------------------------------
template<int K_STEPS, bool RELU, bool TO_GLOBAL>
__device__ __forceinline__ void mfma_layer32(
    const char* inbuf, char* outbuf, float* gout, int pbase,
    const short* __restrict__ wpack, int woff, int sz, int N,
    const float* __restrict__ bias, int mt, int nt, int lane, int out_col_off)
{
    f32x4 acc = (f32x4){0.f, 0.f, 0.f, 0.f};
    const int m_a  = mt * 16 + (lane & 15);
    const int kb   = lane >> 4;
    const int swzA = (m_a & 7) << 4;
    const int n    = nt * 16 + (lane & 15);

    #pragma unroll
    for (int ks = 0; ks < K_STEPS; ++ks) {
        const int boff = m_a * 512 + ks * 128 + kb * 32;
        f32x4 a0 = *(const f32x4*)(inbuf + ((boff     ) ^ swzA));
        f32x4 a1 = *(const f32x4*)(inbuf + ((boff + 16) ^ swzA));
        short8 ahi, alo;
        #pragma unroll
        for (int i2 = 0; i2 < 8; ++i2) {
            float v = (i2 < 4) ? a0[i2] : a1[i2 - 4];
            short h = f2bf_bits(v);
            ahi[i2] = h;
            alo[i2] = f2bf_bits(v - bf2f_bits(h));
        }
        const int wi = woff + ((ks * N + n) * 4 + kb) * 8;
        short8 whi = *(const short8*)(wpack + wi);
        short8 wlo = *(const short8*)(wpack + wi + sz);
        acc = __builtin_amdgcn_mfma_f32_16x16x32_bf16(ahi, whi, acc, 0, 0, 0);
        acc = __builtin_amdgcn_mfma_f32_16x16x32_bf16(ahi, wlo, acc, 0, 0, 0);
        acc = __builtin_amdgcn_mfma_f32_16x16x32_bf16(alo, whi, acc, 0, 0, 0);
    }

    const float bv = bias[n];
    #pragma unroll
    for (int r = 0; r < 4; ++r) {
        float v = acc[r] + bv;
        if (RELU) v = fmaxf(v, 0.0f);
        const int pw = mt * 16 + (lane >> 4) * 4 + r;
        if (TO_GLOBAL) {
            gout[(size_t)(pbase + pw) * 64 + n] = v;
        } else {
            const int w = out_col_off + n;
            *(float*)(outbuf + (((pw * 512 + (w >> 2) * 16) ^ ((pw & 7) << 4)) + (w & 3) * 4)) = v;
        }
    }
}

// ---------------------------------------------------------------------------
// fused_kernel: grid 512; XCD-aware swizzle keeps all 8 quarters of a window
// on one XCD (L2 locality).  block 1024 (16 waves), 32 px per block.
// Phase 1: stage transposed window (bufA = xsT, 32 KB) + zero feat-pad cols.
// Phase 2: 2 passes x 16 waves: fp32 distances -> radix top-20 -> fp64 re-rank
//          (split across lanes 0..19 / 32..51), feat written into swizzled b0.
// Phase 3: 6 FFN layers via MFMA, ping-pong b0 <-> bufA (aliases dead xsT).
// NOTE: plain __launch_bounds__(1024) — a min-waves floor of 8 caps VGPR at 64
// and spills xi[32] to scratch (R7: 147 MB scratch writes, 2x slowdown).
// ---------------------------------------------------------------------------
__global__ __launch_bounds__(1024) void fused_kernel(
    const float* __restrict__ x,     // (16384, 32)
    const short* __restrict__ wpack,
    const float* __restrict__ s0b, const float* __restrict__ s1b,
    const float* __restrict__ sob, const float* __restrict__ o0b,
    const float* __restrict__ o1b, const float* __restrict__ oob,
    float* __restrict__ out)         // (16384, 64)
{
    __shared__ __align__(16) float bufA[8192];   // 32 KB: xsT, then FFN pong
    __shared__ __align__(16) float buf0[4096];   // 16 KB: feat/FFN ping
    __shared__ int    candj[16][NCAND];
    __shared__ double rs[16][NCAND];

    const int tid   = threadIdx.x;
    const int lane  = tid & 63;
    const int wv    = tid >> 6;
    // XCD-aware swizzle (512 = 8 xcd x 8 win x 8 qr, bijective):
    const int xcd   = blockIdx.x & 7;
    const int sub   = blockIdx.x >> 3;           // 0..63
    const int win   = xcd * 8 + (sub >> 3);      // 0..63
    const int qr    = sub & 7;                   // 0..7
    const int pbase = win * 256 + qr * 32;
    char* bA = (char*)bufA;
    char* b0 = (char*)buf0;

    // ---- stage window transposed: x[j][c] -> granule (c*64 + (j&63)^((c>>2)&7)), word (j>>6)
    if (tid < 512) {
        const int c4 = tid & 7, jb = tid >> 3;    // jb in [0,64)
        const float4* gx = reinterpret_cast<const float4*>(x + (size_t)win * 8192);
        float4 v0 = gx[jb * 8 + c4];
        float4 v1 = gx[jb * 8 + c4 + 512];
        float4 v2 = gx[jb * 8 + c4 + 1024];
        float4 v3 = gx[jb * 8 + c4 + 1536];
        float4* xsT4 = reinterpret_cast<float4*>(bufA);
        const int gsw = jb ^ c4;
        xsT4[(4 * c4 + 0) * 64 + gsw] = make_float4(v0.x, v1.x, v2.x, v3.x);
        xsT4[(4 * c4 + 1) * 64 + gsw] = make_float4(v0.y, v1.y, v2.y, v3.y);
        xsT4[(4 * c4 + 2) * 64 + gsw] = make_float4(v0.z, v1.z, v2.z, v3.z);
        xsT4[(4 * c4 + 3) * 64 + gsw] = make_float4(v0.w, v1.w, v2.w, v3.w);
    } else if (tid < 640) {
        int u = tid - 512, p = u >> 2, j = u & 3;  // zero feat cols 48..63
        *(f32x4*)(b0 + ((p * 512 + (12 + j) * 16) ^ ((p & 7) << 4))) = (f32x4){0.f,0.f,0.f,0.f};
    }
    __syncthreads();

    // ---- simtopk: 2 passes, wave handles window-local pixel qr*32 + t*16 + wv
    for (int t = 0; t < 2; ++t) {
        const int iu = __builtin_amdgcn_readfirstlane(qr * 32 + t * 16 + wv);
        const float* xrow = x + (size_t)win * 8192 + (size_t)iu * 32;
        float xi[32];
        #pragma unroll
        for (int c = 0; c < 32; ++c) xi[c] = xrow[c];

        const f32x4* xsT4c = (const f32x4*)bufA;
        float a0 = 0.f, a1 = 0.f, a2 = 0.f, a3 = 0.f;
        #pragma unroll
        for (int c = 0; c < 32; ++c) {
            f32x4 a = xsT4c[c * 64 + (lane ^ ((c >> 2) & 7))];
            a0 += fabsf(a[0] - xi[c]);
            a1 += fabsf(a[1] - xi[c]);
            a2 += fabsf(a[2] - xi[c]);
            a3 += fabsf(a[3] - xi[c]);
        }
        unsigned int p[4];
        p[0] = (__float_as_uint(a0) & 0xFFFFFF00u) | (unsigned)(lane);
        p[1] = (__float_as_uint(a1) & 0xFFFFFF00u) | (unsigned)(lane + 64);
        p[2] = (__float_as_uint(a2) & 0xFFFFFF00u) | (unsigned)(lane + 128);
        p[3] = (__float_as_uint(a3) & 0xFFFFFF00u) | (unsigned)(lane + 192);

        // radix-select threshold T = NCAND-th smallest (keys unique)
        unsigned int T = 0;
        for (int bit = 31; bit >= 0; --bit) {
            unsigned int cand = T | (1u << bit);
            int cnt = __popcll(__ballot(p[0] < cand)) + __popcll(__ballot(p[1] < cand))
                    + __popcll(__ballot(p[2] < cand)) + __popcll(__ballot(p[3] < cand));
            if (cnt < NCAND) T = cand;
        }

        // compact selected (p <= T: exactly NCAND) into per-wave LDS
        const unsigned long long ltm = (1ull << lane) - 1ull;
        int cbase = 0;
        #pragma unroll
        for (int q = 0; q < 4; ++q) {
            bool sel = (p[q] <= T);
            unsigned long long m = __ballot(sel);
            if (sel) candj[wv][cbase + __popcll(m & ltm)] = q * 64 + lane;
            cbase += __popcll(m);
        }
        asm volatile("s_waitcnt lgkmcnt(0)" ::: "memory");

        // fp64 re-rank, split: lanes 0..19 channels 0..15, lanes 32..51 channels 16..31
        const int cl = lane & 31;
        double s = 0.0;
        int myj = -1;
        if (cl < NCAND) {
            myj = candj[wv][cl];
            const int jl = myj & 63, jq = myj >> 6;
            const int c0 = (lane >> 5) * 16;
            #pragma unroll
            for (int cc = 0; cc < 16; ++cc) {
                const int c = c0 + cc;
                float bvf = bufA[(c * 64 + (jl ^ ((c >> 2) & 7))) * 4 + jq];
                s += fabs((double)xi[c] - (double)bvf);
            }
        }
        double oth = __shfl(s, lane + 32, 64);
        if (lane < NCAND) {
            s += oth;
            rs[wv][lane] = s;
        }
        asm volatile("s_waitcnt lgkmcnt(0)" ::: "memory");

        if (lane < NCAND) {
            int rank = 0;
            #pragma unroll 4
            for (int o = 0; o < NCAND; ++o) {
                double so = rs[wv][o];
                int    jo = candj[wv][o];
                rank += (so < s || (so == s && jo < myj)) ? 1 : 0;
            }
            if (rank < K_SEL) {
                const int pl = t * 16 + wv;      // block-local pixel row 0..31
                const int rsw = (pl & 7) << 4;
                // score at word col = rank
                *(float*)(b0 + (((pl * 512 + (rank >> 2) * 16) ^ rsw) + (rank & 3) * 4)) =
                    (float)(1.0 - s * 0.03125);
                // rel-pos float2 at word cols {16+2r, 17+2r}
                const int w2 = 16 + 2 * rank;
                float dh = (float)((iu >> 4) - (myj >> 4)) * (1.0f / 15.0f);
                float dw = (float)((iu & 15) - (myj & 15)) * (1.0f / 15.0f);
                *(float2*)(b0 + (((pl * 512 + (w2 >> 2) * 16) ^ rsw) + (w2 & 3) * 4)) =
                    make_float2(dh, dw);
            }
        }
    }
    __syncthreads();

    // ---- FFN phase: b0 (feat+zeros) -> ... -> out
    const int mt = wv & 1, nt = wv >> 1;

    // L1: 48(+16 pad) -> 128 relu   (b0 -> bA)
    mfma_layer32<2, true, false>(b0, bA, nullptr, pbase, wpack, 0, 8192, 128, s0b, mt, nt, lane, 0);
    __syncthreads();
    // L2: 128 -> 128 relu  (bA -> b0)
    mfma_layer32<4, true, false>(bA, b0, nullptr, pbase, wpack, 16384, 16384, 128, s1b, mt, nt, lane, 0);
    __syncthreads();
    // stage x into bA cols 0..31  +  L3: 128 -> 64 (sf, no relu) into bA cols 32..95
    if (tid < 256) {
        int p = tid >> 3, j = tid & 7;
        *(f32x4*)(bA + ((p * 512 + j * 16) ^ ((p & 7) << 4))) =
            ((const f32x4*)x)[(size_t)(pbase + p) * 8 + j];
    }
    if (wv < 8)
        mfma_layer32<4, false, false>(b0, bA, nullptr, pbase, wpack, 49152, 8192, 64, sob, wv & 1, wv >> 1, lane, 32);
    __syncthreads();
    // L4: 96 -> 128 relu  (bA -> b0)
    mfma_layer32<3, true, false>(bA, b0, nullptr, pbase, wpack, 65536, 12288, 128, o0b, mt, nt, lane, 0);
    __syncthreads();
    // L5: 128 -> 128 relu  (b0 -> bA)
    mfma_layer32<4, true, false>(b0, bA, nullptr, pbase, wpack, 90112, 16384, 128, o1b, mt, nt, lane, 0);
    __syncthreads();
    // L6: 128 -> 64 (+bias) -> out
    if (wv < 8)
        mfma_layer32<4, false, true>(bA, nullptr, out, pbase, wpack, 122880, 8192, 64, oob, wv & 1, wv >> 1, lane, 0);
}

extern "C" void kernel_launch(void* const* d_in, const int* in_sizes, int n_in,
                              void* d_out, int out_size, void* d_ws, size_t ws_size,
                              hipStream_t stream) {
    const float* x    = (const float*)d_in[0];
    const float* s0w  = (const float*)d_in[1];
    const float* s0b  = (const float*)d_in[2];
    const float* s1w  = (const float*)d_in[3];
    const float* s1b  = (const float*)d_in[4];
    const float* sow  = (const float*)d_in[5];
    const float* sob  = (const float*)d_in[6];
    const float* o0w  = (const float*)d_in[7];
    const float* o0b  = (const float*)d_in[8];
    const float* o1w  = (const float*)d_in[9];
    const float* o1b  = (const float*)d_in[10];
    const float* oow  = (const float*)d_in[11];
    const float* oob  = (const float*)d_in[12];

    short* wpack = (short*)d_ws;                 // 139264 shorts = 278528 B
    float* out   = (float*)d_out;

    pack_kernel<<<272, 256, 0, stream>>>(s0w, s1w, sow, o0w, o1w, oow, wpack);
    fused_kernel<<<512, 1024, 0, stream>>>(x, wpack,
                                           s0b, s1b, sob, o0b, o1b, oob,
                                           out);
}

// Round 9
// 70.017 us; speedup vs baseline: 1.2001x; 1.2001x over previous
//
#include <hip/hip_runtime.h>
#include <hip/hip_bf16.h>

#define K_SEL 16
#define NCAND 20

typedef __attribute__((ext_vector_type(8))) short short8;
typedef __attribute__((ext_vector_type(4))) short short4v;
typedef __attribute__((ext_vector_type(4))) float f32x4;

__device__ __forceinline__ short f2bf_bits(float v) {
    union { __hip_bfloat16 b; short s; } u;
    u.b = __float2bfloat16(v);                    // RNE HW convert
    return u.s;
}
__device__ __forceinline__ float bf2f_bits(short h) {
    return __uint_as_float(((unsigned)(unsigned short)h) << 16);
}

// ---------------------------------------------------------------------------
// Kernel 1: simtopk v4 (R6-proven) + absorbed weight-pack (blocks 0..67).
// grid 1024 = 64 win x 16 groups; block 1024 thr = 16 waves, 1 pixel/wave.
// Distances fp32 on transposed-swizzled LDS; radix-select top-20 (ballot);
// fp64 re-rank split across lane halves -> exact top-16 order.
// ---------------------------------------------------------------------------
__global__ __launch_bounds__(1024) void simtopk_kernel(
    const float* __restrict__ x,    // (64, 256, 32) fp32
    float* __restrict__ feat,       // (16384, 48)   [16 scores | 32 relpos]
    const float* __restrict__ s0w, const float* __restrict__ s1w,
    const float* __restrict__ sow, const float* __restrict__ o0w,
    const float* __restrict__ o1w, const float* __restrict__ oow,
    short* __restrict__ wpack)
{
    __shared__ __align__(16) float xsT[8192];     // 32 KB transposed window
    __shared__ int    candj[16][NCAND];
    __shared__ double rs[16][NCAND];

    const int tid  = threadIdx.x;
    const int win  = blockIdx.x >> 4;
    const int grp  = blockIdx.x & 15;
    const int lane = tid & 63;
    const int wv   = tid >> 6;

    // ---- absorbed pack: one-off split-bf16 weight repack (blocks 0..67) ----
    {
        int t = blockIdx.x * 1024 + tid;
        if (t < 69632) {
            int l, base;
            if      (t <  8192) { l = 0; base = 0;     }
            else if (t < 24576) { l = 1; base = 8192;  }
            else if (t < 32768) { l = 2; base = 24576; }
            else if (t < 45056) { l = 3; base = 32768; }
            else if (t < 61440) { l = 4; base = 45056; }
            else                { l = 5; base = 61440; }
            const float* W = (l == 0) ? s0w : (l == 1) ? s1w : (l == 2) ? sow
                           : (l == 3) ? o0w : (l == 4) ? o1w : oow;
            int N    = (l == 2 || l == 5) ? 64 : 128;
            int Kr   = (l == 0) ? 48 : (l == 3) ? 96 : 128;
            int woff = (l == 0) ? 0 : (l == 1) ? 16384 : (l == 2) ? 49152
                     : (l == 3) ? 65536 : (l == 4) ? 90112 : 122880;
            int sz   = (l == 2 || l == 5) ? 8192 : (l == 3) ? 12288 : (l == 0) ? 8192 : 16384;
            int e = t - base;
            int i = e & 7, kb = (e >> 3) & 3, rem = e >> 5;
            int n = rem % N, ks = rem / N;
            int k = ks * 32 + kb * 8 + i;
            float v = (k < Kr) ? W[k * N + n] : 0.0f;
            short hi = f2bf_bits(v);
            float lo = v - bf2f_bits(hi);
            wpack[woff + e]      = hi;
            wpack[woff + sz + e] = f2bf_bits(lo);
        }
    }

    // ---- stage window transposed: x[j][c] -> granule (c*64 + (j&63)^((c>>2)&7)), word (j>>6)
    if (tid < 512) {
        const int c4 = tid & 7, jb = tid >> 3;    // jb in [0,64)
        const float4* gx = reinterpret_cast<const float4*>(x + (size_t)win * 8192);
        float4 v0 = gx[jb * 8 + c4];
        float4 v1 = gx[jb * 8 + c4 + 512];
        float4 v2 = gx[jb * 8 + c4 + 1024];
        float4 v3 = gx[jb * 8 + c4 + 1536];
        float4* xsT4 = reinterpret_cast<float4*>(xsT);
        const int gsw = jb ^ c4;
        xsT4[(4 * c4 + 0) * 64 + gsw] = make_float4(v0.x, v1.x, v2.x, v3.x);
        xsT4[(4 * c4 + 1) * 64 + gsw] = make_float4(v0.y, v1.y, v2.y, v3.y);
        xsT4[(4 * c4 + 2) * 64 + gsw] = make_float4(v0.z, v1.z, v2.z, v3.z);
        xsT4[(4 * c4 + 3) * 64 + gsw] = make_float4(v0.w, v1.w, v2.w, v3.w);
    }

    // ---- xi row via wave-uniform scalar loads (overlaps staging) ----
    const int iu = __builtin_amdgcn_readfirstlane(grp * 16 + wv);
    const float* xrow = x + (size_t)win * 8192 + (size_t)iu * 32;
    float xi[32];
    #pragma unroll
    for (int c = 0; c < 32; ++c) xi[c] = xrow[c];

    __syncthreads();

    // ---- fp32 |delta| sums: lane owns j = lane + 64q via one b128 per channel ----
    const f32x4* xsT4c = reinterpret_cast<const f32x4*>(xsT);
    float a0 = 0.f, a1 = 0.f, a2 = 0.f, a3 = 0.f;
    #pragma unroll
    for (int c = 0; c < 32; ++c) {
        f32x4 a = xsT4c[c * 64 + (lane ^ ((c >> 2) & 7))];
        a0 += fabsf(a[0] - xi[c]);
        a1 += fabsf(a[1] - xi[c]);
        a2 += fabsf(a[2] - xi[c]);
        a3 += fabsf(a[3] - xi[c]);
    }
    unsigned int p[4];
    p[0] = (__float_as_uint(a0) & 0xFFFFFF00u) | (unsigned)(lane);
    p[1] = (__float_as_uint(a1) & 0xFFFFFF00u) | (unsigned)(lane + 64);
    p[2] = (__float_as_uint(a2) & 0xFFFFFF00u) | (unsigned)(lane + 128);
    p[3] = (__float_as_uint(a3) & 0xFFFFFF00u) | (unsigned)(lane + 192);

    // ---- radix-select: T = NCAND-th smallest packed key (keys unique) ----
    unsigned int T = 0;
    for (int bit = 31; bit >= 0; --bit) {
        unsigned int cand = T | (1u << bit);
        int cnt = __popcll(__ballot(p[0] < cand)) + __popcll(__ballot(p[1] < cand))
                + __popcll(__ballot(p[2] < cand)) + __popcll(__ballot(p[3] < cand));
        if (cnt < NCAND) T = cand;
    }

    // ---- compact selected (p <= T: exactly NCAND) into per-wave LDS ----
    const unsigned long long ltm = (1ull << lane) - 1ull;
    int cbase = 0;
    #pragma unroll
    for (int q = 0; q < 4; ++q) {
        bool sel = (p[q] <= T);
        unsigned long long m = __ballot(sel);
        if (sel) candj[wv][cbase + __popcll(m & ltm)] = q * 64 + lane;
        cbase += __popcll(m);
    }
    asm volatile("s_waitcnt lgkmcnt(0)" ::: "memory");

    // ---- fp64 re-rank, split: lanes 0..19 ch 0..15, lanes 32..51 ch 16..31 ----
    const int cl = lane & 31;
    double s = 0.0;
    int myj = -1;
    if (cl < NCAND) {
        myj = candj[wv][cl];
        const int jl = myj & 63, jq = myj >> 6;
        const int c0 = (lane >> 5) * 16;
        #pragma unroll
        for (int cc = 0; cc < 16; ++cc) {
            const int c = c0 + cc;
            float bvf = xsT[(c * 64 + (jl ^ ((c >> 2) & 7))) * 4 + jq];
            s += fabs((double)xi[c] - (double)bvf);
        }
    }
    double oth = __shfl(s, lane + 32, 64);
    if (lane < NCAND) {
        s += oth;
        rs[wv][lane] = s;
    }
    asm volatile("s_waitcnt lgkmcnt(0)" ::: "memory");

    if (lane < NCAND) {
        int rank = 0;
        #pragma unroll 4
        for (int o = 0; o < NCAND; ++o) {
            double so = rs[wv][o];
            int    jo = candj[wv][o];
            rank += (so < s || (so == s && jo < myj)) ? 1 : 0;
        }
        if (rank < K_SEL) {
            const int gp = win * 256 + iu;
            feat[gp * 48 + rank] = (float)(1.0 - s * 0.03125);
            float dh = (float)((iu >> 4) - (myj >> 4)) * (1.0f / 15.0f);
            float dw = (float)((iu & 15) - (myj & 15)) * (1.0f / 15.0f);
            reinterpret_cast<float2*>(feat)[gp * 24 + 8 + rank] = make_float2(dh, dw);
        }
    }
}

// ---------------------------------------------------------------------------
// Kernel 2: FFN with bf16 hi/lo activation PLANES in LDS (split at produce
// time, consumed directly as MFMA A-fragments -> zero per-K-step cvt VALU).
// 32 px/block, grid 512 (2 blocks/CU), 16 waves: mt = wv&1, nt = wv>>1.
// Plane layout: row p stride 256 B; 16B granule g = col>>3, swizzled g^(p&7).
// C/D: col = lane&15, row = (lane>>4)*4 + r   [m89/m91 verified]
// ---------------------------------------------------------------------------
template<int K_STEPS, int N, bool RELU, bool TO_GLOBAL>
__device__ __forceinline__ void bf16_layer(
    const short* hiIn, const short* loIn, short* hiOut, short* loOut,
    float* gout, int pbase, const short* __restrict__ wpack, int woff, int sz,
    const float* __restrict__ bias, int wv, int lane, int out_col_off)
{
    if (N == 64 && wv >= 8) return;
    const int mt  = wv & 1;
    const int nt  = wv >> 1;
    const int m_a = mt * 16 + (lane & 15);
    const int kb  = lane >> 4;
    const int n   = nt * 16 + (lane & 15);

    f32x4 acc = (f32x4){0.f, 0.f, 0.f, 0.f};
    #pragma unroll
    for (int ks = 0; ks < K_STEPS; ++ks) {
        const int g   = ks * 4 + kb;
        const int off = m_a * 256 + ((g ^ (m_a & 7)) << 4);
        short8 ahi = *(const short8*)((const char*)hiIn + off);
        short8 alo = *(const short8*)((const char*)loIn + off);
        const int wi = woff + ((ks * N + n) * 4 + kb) * 8;
        short8 whi = *(const short8*)(wpack + wi);
        short8 wlo = *(const short8*)(wpack + wi + sz);
        acc = __builtin_amdgcn_mfma_f32_16x16x32_bf16(ahi, whi, acc, 0, 0, 0);
        acc = __builtin_amdgcn_mfma_f32_16x16x32_bf16(ahi, wlo, acc, 0, 0, 0);
        acc = __builtin_amdgcn_mfma_f32_16x16x32_bf16(alo, whi, acc, 0, 0, 0);
    }

    const float bv = bias[n];
    #pragma unroll
    for (int r = 0; r < 4; ++r) {
        float v = acc[r] + bv;
        if (RELU) v = fmaxf(v, 0.0f);
        const int pw = mt * 16 + (lane >> 4) * 4 + r;
        if (TO_GLOBAL) {
            gout[(size_t)(pbase + pw) * 64 + n] = v;
        } else {
            const int w   = out_col_off + n;
            const int off = pw * 256 + ((((w >> 3) ^ (pw & 7))) << 4) + (w & 7) * 2;
            short h = f2bf_bits(v);
            short l = f2bf_bits(v - bf2f_bits(h));
            *(short*)((char*)hiOut + off) = h;
            *(short*)((char*)loOut + off) = l;
        }
    }
}

__global__ __launch_bounds__(1024) void ffn_kernel(
    const float* __restrict__ x,     // (16384, 32)
    const float* __restrict__ feat,  // (16384, 48)
    const short* __restrict__ wpack,
    const float* __restrict__ s0b, const float* __restrict__ s1b,
    const float* __restrict__ sob, const float* __restrict__ o0b,
    const float* __restrict__ o1b, const float* __restrict__ oob,
    float* __restrict__ out)         // (16384, 64)
{
    __shared__ __align__(16) short hiA[32 * 128];   // 8 KB each
    __shared__ __align__(16) short loA[32 * 128];
    __shared__ __align__(16) short hiB[32 * 128];
    __shared__ __align__(16) short loB[32 * 128];

    const int tid   = threadIdx.x;
    const int lane  = tid & 63;
    const int wv    = tid >> 6;
    const int pbase = blockIdx.x * 32;

    // ---- stage feat (cols 0..47, split) + zero cols 48..63 into planes A ----
    if (tid < 384) {
        int p = tid / 12, c4 = tid - p * 12;                  // 4-col group
        f32x4 v = ((const f32x4*)feat)[(size_t)(pbase + p) * 12 + c4];
        short4v h4, l4;
        #pragma unroll
        for (int j = 0; j < 4; ++j) {
            short h = f2bf_bits(v[j]);
            h4[j] = h;
            l4[j] = f2bf_bits(v[j] - bf2f_bits(h));
        }
        int off = p * 256 + ((((c4 >> 1) ^ (p & 7))) << 4) + (c4 & 1) * 8;
        *(short4v*)((char*)hiA + off) = h4;
        *(short4v*)((char*)loA + off) = l4;
    } else if (tid < 512) {
        int t2 = tid - 384;                                   // 0..127
        int p = t2 & 31, sel = t2 >> 5;                       // 32 rows x 4 tasks
        int g = 6 + (sel & 1);
        int off = p * 256 + ((g ^ (p & 7)) << 4);
        short8 z = (short8){0,0,0,0,0,0,0,0};
        if (sel >> 1) *(short8*)((char*)loA + off) = z;
        else          *(short8*)((char*)hiA + off) = z;
    }
    __syncthreads();

    // L1: 48(+pad) -> 128 relu   (A -> B)
    bf16_layer<2, 128, true, false>(hiA, loA, hiB, loB, nullptr, pbase,
                                    wpack, 0, 8192, s0b, wv, lane, 0);
    __syncthreads();
    // L2: 128 -> 128 relu  (B -> A)
    bf16_layer<4, 128, true, false>(hiB, loB, hiA, loA, nullptr, pbase,
                                    wpack, 16384, 16384, s1b, wv, lane, 0);
    __syncthreads();
    // L3: 128 -> 64 (sf, no relu) into B cols 32..95 ; stage x into B cols 0..31
    if (tid < 256) {
        int p = tid >> 3, c4 = tid & 7;
        f32x4 v = ((const f32x4*)x)[(size_t)(pbase + p) * 8 + c4];
        short4v h4, l4;
        #pragma unroll
        for (int j = 0; j < 4; ++j) {
            short h = f2bf_bits(v[j]);
            h4[j] = h;
            l4[j] = f2bf_bits(v[j] - bf2f_bits(h));
        }
        int off = p * 256 + ((((c4 >> 1) ^ (p & 7))) << 4) + (c4 & 1) * 8;
        *(short4v*)((char*)hiB + off) = h4;
        *(short4v*)((char*)loB + off) = l4;
    }
    bf16_layer<4, 64, false, false>(hiA, loA, hiB, loB, nullptr, pbase,
                                    wpack, 49152, 8192, sob, wv, lane, 32);
    __syncthreads();
    // L4: 96 -> 128 relu  (B -> A)
    bf16_layer<3, 128, true, false>(hiB, loB, hiA, loA, nullptr, pbase,
                                    wpack, 65536, 12288, o0b, wv, lane, 0);
    __syncthreads();
    // L5: 128 -> 128 relu  (A -> B)
    bf16_layer<4, 128, true, false>(hiA, loA, hiB, loB, nullptr, pbase,
                                    wpack, 90112, 16384, o1b, wv, lane, 0);
    __syncthreads();
    // L6: 128 -> 64 (+bias) -> out
    bf16_layer<4, 64, false, true>(hiB, loB, nullptr, nullptr, out, pbase,
                                   wpack, 122880, 8192, oob, wv, lane, 0);
}

extern "C" void kernel_launch(void* const* d_in, const int* in_sizes, int n_in,
                              void* d_out, int out_size, void* d_ws, size_t ws_size,
                              hipStream_t stream) {
    const float* x    = (const float*)d_in[0];
    const float* s0w  = (const float*)d_in[1];
    const float* s0b  = (const float*)d_in[2];
    const float* s1w  = (const float*)d_in[3];
    const float* s1b  = (const float*)d_in[4];
    const float* sow  = (const float*)d_in[5];
    const float* sob  = (const float*)d_in[6];
    const float* o0w  = (const float*)d_in[7];
    const float* o0b  = (const float*)d_in[8];
    const float* o1w  = (const float*)d_in[9];
    const float* o1b  = (const float*)d_in[10];
    const float* oow  = (const float*)d_in[11];
    const float* oob  = (const float*)d_in[12];

    short* wpack = (short*)d_ws;                      // 278528 B
    float* feat  = (float*)((char*)d_ws + 524288);    // 16384*48 fp32
    float* out   = (float*)d_out;

    simtopk_kernel<<<1024, 1024, 0, stream>>>(x, feat,
                                              s0w, s1w, sow, o0w, o1w, oow, wpack);
    ffn_kernel<<<512, 1024, 0, stream>>>(x, feat, wpack,
                                         s0b, s1b, sob, o0b, o1b, oob,
                                         out);
}

// Round 10
// 58.543 us; speedup vs baseline: 1.4354x; 1.1960x over previous
//
#include <hip/hip_runtime.h>
#include <hip/hip_bf16.h>

#define K_SEL 16
#define NCAND 20

typedef __attribute__((ext_vector_type(8))) short short8;
typedef __attribute__((ext_vector_type(4))) short short4v;
typedef __attribute__((ext_vector_type(4))) float f32x4;

__device__ __forceinline__ short f2bf_bits(float v) {
    union { __hip_bfloat16 b; short s; } u;
    u.b = __float2bfloat16(v);                    // RNE HW convert
    return u.s;
}
__device__ __forceinline__ float bf2f_bits(short h) {
    return __uint_as_float(((unsigned)(unsigned short)h) << 16);
}

// ---------------------------------------------------------------------------
// Kernel A — EXACT R6 source (measured ~33 us): channel-major LDS
// (register-transpose staging), fp32 distances, 32-bit radix-select
// (ballot/popc) for the exact top-20 set, fp64 re-rank on lanes 0..19.
// grid: 1024 blocks = 64 windows x 16 pixel-groups; block = 1024 thr.
// NOTE (R9 lesson): do NOT absorb extra work or split the re-rank — both
// perturb regalloc (VGPR 44->32, xi[] into SGPRs) and cost +60% duration.
// ---------------------------------------------------------------------------
__global__ __launch_bounds__(1024) void simtopk_kernel(
    const float* __restrict__ x,    // (64, 256, 32) fp32
    float* __restrict__ feat)       // (16384, 48)   [16 scores | 32 relpos]
{
    __shared__ __align__(16) float xsT[8192];     // 32 KB transposed window
    __shared__ int    candj[16][NCAND];
    __shared__ double rs[16][NCAND];

    const int tid  = threadIdx.x;
    const int win  = blockIdx.x >> 4;
    const int grp  = blockIdx.x & 15;
    const int lane = tid & 63;
    const int wv   = tid >> 6;

    // ---- staging: threads 0..511 each load a 4j x 4c block and transpose ----
    if (tid < 512) {
        const int c4 = tid & 7, jb = tid >> 3;    // jb in [0,64)
        const float4* gx = reinterpret_cast<const float4*>(x + (size_t)win * 8192);
        float4 v0 = gx[jb * 8 + c4];              // x[jb      ][4c4..]
        float4 v1 = gx[jb * 8 + c4 + 512];        // x[jb + 64 ][4c4..]
        float4 v2 = gx[jb * 8 + c4 + 1024];       // x[jb + 128][4c4..]
        float4 v3 = gx[jb * 8 + c4 + 1536];       // x[jb + 192][4c4..]
        float4* xsT4 = reinterpret_cast<float4*>(xsT);
        const int gsw = jb ^ c4;                  // (c>>2)&7 == c4 for all 4 c's
        xsT4[(4 * c4 + 0) * 64 + gsw] = make_float4(v0.x, v1.x, v2.x, v3.x);
        xsT4[(4 * c4 + 1) * 64 + gsw] = make_float4(v0.y, v1.y, v2.y, v3.y);
        xsT4[(4 * c4 + 2) * 64 + gsw] = make_float4(v0.z, v1.z, v2.z, v3.z);
        xsT4[(4 * c4 + 3) * 64 + gsw] = make_float4(v0.w, v1.w, v2.w, v3.w);
    }

    // ---- xi row via wave-uniform scalar loads (overlaps staging) ----
    const int iu = __builtin_amdgcn_readfirstlane(grp * 16 + wv);
    const float* xrow = x + (size_t)win * 8192 + (size_t)iu * 32;
    float xi[32];
    #pragma unroll
    for (int c = 0; c < 32; ++c) xi[c] = xrow[c];

    __syncthreads();

    // ---- fp32 |delta| sums: lane owns j = lane + 64q via one b128 per channel ----
    const float4* xsT4c = reinterpret_cast<const float4*>(xsT);
    float a0 = 0.f, a1 = 0.f, a2 = 0.f, a3 = 0.f;
    #pragma unroll
    for (int c = 0; c < 32; ++c) {
        float4 a = xsT4c[c * 64 + (lane ^ ((c >> 2) & 7))];
        a0 += fabsf(a.x - xi[c]);
        a1 += fabsf(a.y - xi[c]);
        a2 += fabsf(a.z - xi[c]);
        a3 += fabsf(a.w - xi[c]);
    }
    unsigned int p[4];
    p[0] = (__float_as_uint(a0) & 0xFFFFFF00u) | (unsigned)(lane);
    p[1] = (__float_as_uint(a1) & 0xFFFFFF00u) | (unsigned)(lane + 64);
    p[2] = (__float_as_uint(a2) & 0xFFFFFF00u) | (unsigned)(lane + 128);
    p[3] = (__float_as_uint(a3) & 0xFFFFFF00u) | (unsigned)(lane + 192);

    // ---- radix-select: T = NCAND-th smallest packed key (keys unique) ----
    unsigned int T = 0;
    for (int bit = 31; bit >= 0; --bit) {
        unsigned int cand = T | (1u << bit);
        int cnt = __popcll(__ballot(p[0] < cand)) + __popcll(__ballot(p[1] < cand))
                + __popcll(__ballot(p[2] < cand)) + __popcll(__ballot(p[3] < cand));
        if (cnt < NCAND) T = cand;
    }

    // ---- compact selected (p <= T: exactly NCAND) into per-wave LDS ----
    const unsigned long long lt = (1ull << lane) - 1ull;
    int base = 0;
    #pragma unroll
    for (int q = 0; q < 4; ++q) {
        bool sel = (p[q] <= T);
        unsigned long long m = __ballot(sel);
        if (sel) candj[wv][base + __popcll(m & lt)] = q * 64 + lane;
        base += __popcll(m);
    }
    asm volatile("s_waitcnt lgkmcnt(0)" ::: "memory");

    // ---- fp64 re-rank (exact order; summation order matches passing code) ----
    double s = 0.0;
    int myj = -1;
    if (lane < NCAND) {
        myj = candj[wv][lane];
        const int jl = myj & 63, jq = myj >> 6;
        #pragma unroll
        for (int c = 0; c < 32; ++c) {
            float bv = xsT[(c * 64 + (jl ^ ((c >> 2) & 7))) * 4 + jq];
            s += fabs((double)xi[c] - (double)bv);
        }
        rs[wv][lane] = s;
    }
    asm volatile("s_waitcnt lgkmcnt(0)" ::: "memory");

    if (myj >= 0) {
        int rank = 0;
        #pragma unroll 4
        for (int o = 0; o < NCAND; ++o) {
            double so = rs[wv][o];
            int    jo = candj[wv][o];
            rank += (so < s || (so == s && jo < myj)) ? 1 : 0;
        }
        if (rank < K_SEL) {
            const int gp = win * 256 + iu;
            feat[gp * 48 + rank] = (float)(1.0 - s * 0.03125);
            float dh = (float)((iu >> 4) - (myj >> 4)) * (1.0f / 15.0f);
            float dw = (float)((iu & 15) - (myj & 15)) * (1.0f / 15.0f);
            reinterpret_cast<float2*>(feat)[gp * 24 + 8 + rank] = make_float2(dh, dw);
        }
    }
}

// ---------------------------------------------------------------------------
// pack_kernel (separate, ~3 us): weights -> split-bf16 hi/lo planes in
// B-fragment order: idx = ((ks*N + n)*4 + kb)*8 + i  <->  W[ks*32+kb*8+i][n].
// ---------------------------------------------------------------------------
__global__ __launch_bounds__(256) void pack_kernel(
    const float* __restrict__ s0w, const float* __restrict__ s1w,
    const float* __restrict__ sow, const float* __restrict__ o0w,
    const float* __restrict__ o1w, const float* __restrict__ oow,
    short* __restrict__ wpack)
{
    int t = blockIdx.x * 256 + threadIdx.x;
    if (t >= 69632) return;
    int l, base;
    if      (t <  8192) { l = 0; base = 0;     }
    else if (t < 24576) { l = 1; base = 8192;  }
    else if (t < 32768) { l = 2; base = 24576; }
    else if (t < 45056) { l = 3; base = 32768; }
    else if (t < 61440) { l = 4; base = 45056; }
    else                { l = 5; base = 61440; }

    const float* W = (l == 0) ? s0w : (l == 1) ? s1w : (l == 2) ? sow
                   : (l == 3) ? o0w : (l == 4) ? o1w : oow;
    int N    = (l == 2 || l == 5) ? 64 : 128;
    int Kr   = (l == 0) ? 48 : (l == 3) ? 96 : 128;
    int woff = (l == 0) ? 0 : (l == 1) ? 16384 : (l == 2) ? 49152
             : (l == 3) ? 65536 : (l == 4) ? 90112 : 122880;
    int sz   = (l == 2 || l == 5) ? 8192 : (l == 3) ? 12288 : (l == 0) ? 8192 : 16384;

    int e = t - base;
    int i = e & 7, kb = (e >> 3) & 3, rem = e >> 5;
    int n = rem % N, ks = rem / N;
    int k = ks * 32 + kb * 8 + i;
    float v = (k < Kr) ? W[k * N + n] : 0.0f;
    short hi = f2bf_bits(v);
    float lo = v - bf2f_bits(hi);
    wpack[woff + e]      = hi;
    wpack[woff + sz + e] = f2bf_bits(lo);
}

// ---------------------------------------------------------------------------
// Kernel B (R9-proven): FFN with bf16 hi/lo activation PLANES in LDS (split
// at produce time, consumed directly as MFMA A-fragments).
// 32 px/block, grid 512 (2 blocks/CU), 16 waves: mt = wv&1, nt = wv>>1.
// Plane layout: row p stride 256 B; 16B granule g = col>>3, swizzled g^(p&7).
// C/D: col = lane&15, row = (lane>>4)*4 + r   [m89/m91 verified]
// ---------------------------------------------------------------------------
template<int K_STEPS, int N, bool RELU, bool TO_GLOBAL>
__device__ __forceinline__ void bf16_layer(
    const short* hiIn, const short* loIn, short* hiOut, short* loOut,
    float* gout, int pbase, const short* __restrict__ wpack, int woff, int sz,
    const float* __restrict__ bias, int wv, int lane, int out_col_off)
{
    if (N == 64 && wv >= 8) return;
    const int mt  = wv & 1;
    const int nt  = wv >> 1;
    const int m_a = mt * 16 + (lane & 15);
    const int kb  = lane >> 4;
    const int n   = nt * 16 + (lane & 15);

    f32x4 acc = (f32x4){0.f, 0.f, 0.f, 0.f};
    #pragma unroll
    for (int ks = 0; ks < K_STEPS; ++ks) {
        const int g   = ks * 4 + kb;
        const int off = m_a * 256 + ((g ^ (m_a & 7)) << 4);
        short8 ahi = *(const short8*)((const char*)hiIn + off);
        short8 alo = *(const short8*)((const char*)loIn + off);
        const int wi = woff + ((ks * N + n) * 4 + kb) * 8;
        short8 whi = *(const short8*)(wpack + wi);
        short8 wlo = *(const short8*)(wpack + wi + sz);
        acc = __builtin_amdgcn_mfma_f32_16x16x32_bf16(ahi, whi, acc, 0, 0, 0);
        acc = __builtin_amdgcn_mfma_f32_16x16x32_bf16(ahi, wlo, acc, 0, 0, 0);
        acc = __builtin_amdgcn_mfma_f32_16x16x32_bf16(alo, whi, acc, 0, 0, 0);
    }

    const float bv = bias[n];
    #pragma unroll
    for (int r = 0; r < 4; ++r) {
        float v = acc[r] + bv;
        if (RELU) v = fmaxf(v, 0.0f);
        const int pw = mt * 16 + (lane >> 4) * 4 + r;
        if (TO_GLOBAL) {
            gout[(size_t)(pbase + pw) * 64 + n] = v;
        } else {
            const int w   = out_col_off + n;
            const int off = pw * 256 + ((((w >> 3) ^ (pw & 7))) << 4) + (w & 7) * 2;
            short h = f2bf_bits(v);
            short l = f2bf_bits(v - bf2f_bits(h));
            *(short*)((char*)hiOut + off) = h;
            *(short*)((char*)loOut + off) = l;
        }
    }
}

__global__ __launch_bounds__(1024) void ffn_kernel(
    const float* __restrict__ x,     // (16384, 32)
    const float* __restrict__ feat,  // (16384, 48)
    const short* __restrict__ wpack,
    const float* __restrict__ s0b, const float* __restrict__ s1b,
    const float* __restrict__ sob, const float* __restrict__ o0b,
    const float* __restrict__ o1b, const float* __restrict__ oob,
    float* __restrict__ out)         // (16384, 64)
{
    __shared__ __align__(16) short hiA[32 * 128];   // 8 KB each
    __shared__ __align__(16) short loA[32 * 128];
    __shared__ __align__(16) short hiB[32 * 128];
    __shared__ __align__(16) short loB[32 * 128];

    const int tid   = threadIdx.x;
    const int lane  = tid & 63;
    const int wv    = tid >> 6;
    const int pbase = blockIdx.x * 32;

    // ---- stage feat (cols 0..47, split) + zero cols 48..63 into planes A ----
    if (tid < 384) {
        int p = tid / 12, c4 = tid - p * 12;                  // 4-col group
        f32x4 v = ((const f32x4*)feat)[(size_t)(pbase + p) * 12 + c4];
        short4v h4, l4;
        #pragma unroll
        for (int j = 0; j < 4; ++j) {
            short h = f2bf_bits(v[j]);
            h4[j] = h;
            l4[j] = f2bf_bits(v[j] - bf2f_bits(h));
        }
        int off = p * 256 + ((((c4 >> 1) ^ (p & 7))) << 4) + (c4 & 1) * 8;
        *(short4v*)((char*)hiA + off) = h4;
        *(short4v*)((char*)loA + off) = l4;
    } else if (tid < 512) {
        int t2 = tid - 384;                                   // 0..127
        int p = t2 & 31, sel = t2 >> 5;                       // 32 rows x 4 tasks
        int g = 6 + (sel & 1);
        int off = p * 256 + ((g ^ (p & 7)) << 4);
        short8 z = (short8){0,0,0,0,0,0,0,0};
        if (sel >> 1) *(short8*)((char*)loA + off) = z;
        else          *(short8*)((char*)hiA + off) = z;
    }
    __syncthreads();

    // L1: 48(+pad) -> 128 relu   (A -> B)
    bf16_layer<2, 128, true, false>(hiA, loA, hiB, loB, nullptr, pbase,
                                    wpack, 0, 8192, s0b, wv, lane, 0);
    __syncthreads();
    // L2: 128 -> 128 relu  (B -> A)
    bf16_layer<4, 128, true, false>(hiB, loB, hiA, loA, nullptr, pbase,
                                    wpack, 16384, 16384, s1b, wv, lane, 0);
    __syncthreads();
    // L3: 128 -> 64 (sf, no relu) into B cols 32..95 ; stage x into B cols 0..31
    if (tid < 256) {
        int p = tid >> 3, c4 = tid & 7;
        f32x4 v = ((const f32x4*)x)[(size_t)(pbase + p) * 8 + c4];
        short4v h4, l4;
        #pragma unroll
        for (int j = 0; j < 4; ++j) {
            short h = f2bf_bits(v[j]);
            h4[j] = h;
            l4[j] = f2bf_bits(v[j] - bf2f_bits(h));
        }
        int off = p * 256 + ((((c4 >> 1) ^ (p & 7))) << 4) + (c4 & 1) * 8;
        *(short4v*)((char*)hiB + off) = h4;
        *(short4v*)((char*)loB + off) = l4;
    }
    bf16_layer<4, 64, false, false>(hiA, loA, hiB, loB, nullptr, pbase,
                                    wpack, 49152, 8192, sob, wv, lane, 32);
    __syncthreads();
    // L4: 96 -> 128 relu  (B -> A)
    bf16_layer<3, 128, true, false>(hiB, loB, hiA, loA, nullptr, pbase,
                                    wpack, 65536, 12288, o0b, wv, lane, 0);
    __syncthreads();
    // L5: 128 -> 128 relu  (A -> B)
    bf16_layer<4, 128, true, false>(hiA, loA, hiB, loB, nullptr, pbase,
                                    wpack, 90112, 16384, o1b, wv, lane, 0);
    __syncthreads();
    // L6: 128 -> 64 (+bias) -> out
    bf16_layer<4, 64, false, true>(hiB, loB, nullptr, nullptr, out, pbase,
                                   wpack, 122880, 8192, oob, wv, lane, 0);
}

extern "C" void kernel_launch(void* const* d_in, const int* in_sizes, int n_in,
                              void* d_out, int out_size, void* d_ws, size_t ws_size,
                              hipStream_t stream) {
    const float* x    = (const float*)d_in[0];
    const float* s0w  = (const float*)d_in[1];
    const float* s0b  = (const float*)d_in[2];
    const float* s1w  = (const float*)d_in[3];
    const float* s1b  = (const float*)d_in[4];
    const float* sow  = (const float*)d_in[5];
    const float* sob  = (const float*)d_in[6];
    const float* o0w  = (const float*)d_in[7];
    const float* o0b  = (const float*)d_in[8];
    const float* o1w  = (const float*)d_in[9];
    const float* o1b  = (const float*)d_in[10];
    const float* oow  = (const float*)d_in[11];
    const float* oob  = (const float*)d_in[12];

    short* wpack = (short*)d_ws;                      // 278528 B
    float* feat  = (float*)((char*)d_ws + 524288);    // 16384*48 fp32
    float* out   = (float*)d_out;

    pack_kernel<<<272, 256, 0, stream>>>(s0w, s1w, sow, o0w, o1w, oow, wpack);
    simtopk_kernel<<<1024, 1024, 0, stream>>>(x, feat);
    ffn_kernel<<<512, 1024, 0, stream>>>(x, feat, wpack,
                                         s0b, s1b, sob, o0b, o1b, oob,
                                         out);
}

// Round 11
// 52.980 us; speedup vs baseline: 1.5861x; 1.1050x over previous
//
#include <hip/hip_runtime.h>
#include <hip/hip_bf16.h>

#define K_SEL 16
#define NCAND 20

typedef __attribute__((ext_vector_type(8))) short short8;
typedef __attribute__((ext_vector_type(4))) short short4v;
typedef __attribute__((ext_vector_type(4))) float f32x4;

__device__ __forceinline__ short f2bf_bits(float v) {
    union { __hip_bfloat16 b; short s; } u;
    u.b = __float2bfloat16(v);                    // RNE HW convert
    return u.s;
}
__device__ __forceinline__ float bf2f_bits(short h) {
    return __uint_as_float(((unsigned)(unsigned short)h) << 16);
}
__device__ __forceinline__ float readlane_f(float v, int l) {
    return __int_as_float(__builtin_amdgcn_readlane(__float_as_int(v), l));
}

// ---------------------------------------------------------------------------
// Kernel A v5: 2 pixels/wave -> halves LDS candidate traffic (R10 analysis:
// distance-pass ds_read_b128 was ~10us/CU of LDS pipe).  xi values come from
// v_readlane of the candidate vector itself (the wave's pixels are inside it);
// the float4 component index comp = grp>>1 is block-uniform -> template.
// Radix-select top-20 per pixel (two interleaved searches), fp64 re-rank
// (lanes 0..19 px0 | 32..51 px1) with UNCHANGED summation order.
// grid 512 = 64 win x 8 groups of 32 px; block 1024 = 16 waves.
// ---------------------------------------------------------------------------
template<int COMP>
__device__ __forceinline__ void simtopk_body(
    const float* __restrict__ x, float* __restrict__ feat,
    float* xsT, int* candj, double* rs, int win, int grp, int tid)
{
    const int lane = tid & 63;
    const int wv   = tid >> 6;

    // ---- stage transposed window (proven R6 code) ----
    if (tid < 512) {
        const int c4 = tid & 7, jb = tid >> 3;
        const float4* gx = reinterpret_cast<const float4*>(x + (size_t)win * 8192);
        float4 v0 = gx[jb * 8 + c4];
        float4 v1 = gx[jb * 8 + c4 + 512];
        float4 v2 = gx[jb * 8 + c4 + 1024];
        float4 v3 = gx[jb * 8 + c4 + 1536];
        float4* xsT4 = reinterpret_cast<float4*>(xsT);
        const int gsw = jb ^ c4;
        xsT4[(4 * c4 + 0) * 64 + gsw] = make_float4(v0.x, v1.x, v2.x, v3.x);
        xsT4[(4 * c4 + 1) * 64 + gsw] = make_float4(v0.y, v1.y, v2.y, v3.y);
        xsT4[(4 * c4 + 2) * 64 + gsw] = make_float4(v0.z, v1.z, v2.z, v3.z);
        xsT4[(4 * c4 + 3) * 64 + gsw] = make_float4(v0.w, v1.w, v2.w, v3.w);
    }
    __syncthreads();

    const int plbase = (grp & 1) * 32 + wv * 2;   // lane of pixel 0; +1 = pixel 1

    // ---- fp32 |delta| sums for 2 pixels per wave ----
    const f32x4* xsT4c = reinterpret_cast<const f32x4*>(xsT);
    float acc0[4] = {0.f, 0.f, 0.f, 0.f};
    float acc1[4] = {0.f, 0.f, 0.f, 0.f};
    #pragma unroll
    for (int c = 0; c < 32; ++c) {
        f32x4 a = xsT4c[c * 64 + (lane ^ ((c >> 2) & 7))];
        float xi0 = readlane_f(a[COMP], plbase);
        float xi1 = readlane_f(a[COMP], plbase + 1);
        #pragma unroll
        for (int q = 0; q < 4; ++q) {
            acc0[q] += fabsf(a[q] - xi0);
            acc1[q] += fabsf(a[q] - xi1);
        }
    }
    unsigned int p0[4], p1[4];
    #pragma unroll
    for (int q = 0; q < 4; ++q) {
        p0[q] = (__float_as_uint(acc0[q]) & 0xFFFFFF00u) | (unsigned)(q * 64 + lane);
        p1[q] = (__float_as_uint(acc1[q]) & 0xFFFFFF00u) | (unsigned)(q * 64 + lane);
    }

    // ---- radix-select: two interleaved threshold searches (keys unique) ----
    unsigned int T0 = 0, T1 = 0;
    for (int bit = 31; bit >= 0; --bit) {
        unsigned int c0 = T0 | (1u << bit), c1 = T1 | (1u << bit);
        int n0 = __popcll(__ballot(p0[0] < c0)) + __popcll(__ballot(p0[1] < c0))
               + __popcll(__ballot(p0[2] < c0)) + __popcll(__ballot(p0[3] < c0));
        int n1 = __popcll(__ballot(p1[0] < c1)) + __popcll(__ballot(p1[1] < c1))
               + __popcll(__ballot(p1[2] < c1)) + __popcll(__ballot(p1[3] < c1));
        if (n0 < NCAND) T0 = c0;
        if (n1 < NCAND) T1 = c1;
    }

    // ---- compact the two exact top-20 sets into per-wave LDS ----
    const unsigned long long lt = (1ull << lane) - 1ull;
    int base0 = 0, base1 = 0;
    #pragma unroll
    for (int q = 0; q < 4; ++q) {
        bool s0 = (p0[q] <= T0);
        unsigned long long m0 = __ballot(s0);
        if (s0) candj[(wv * 2 + 0) * NCAND + base0 + __popcll(m0 & lt)] = q * 64 + lane;
        base0 += __popcll(m0);
        bool s1 = (p1[q] <= T1);
        unsigned long long m1 = __ballot(s1);
        if (s1) candj[(wv * 2 + 1) * NCAND + base1 + __popcll(m1 & lt)] = q * 64 + lane;
        base1 += __popcll(m1);
    }
    asm volatile("s_waitcnt lgkmcnt(0)" ::: "memory");

    // ---- fp64 re-rank: lanes 0..19 px0, lanes 32..51 px1 (order unchanged) ----
    const int t  = lane >> 5;
    const int cl = lane & 31;
    double s = 0.0;
    int myj = -1;
    if (cl < NCAND) {
        myj = candj[(wv * 2 + t) * NCAND + cl];
        const int jl = myj & 63, jq = myj >> 6;
        const int pl = plbase + t;
        #pragma unroll
        for (int c = 0; c < 32; ++c) {
            float xiv = xsT[(c * 64 + (pl ^ ((c >> 2) & 7))) * 4 + COMP];
            float bv  = xsT[(c * 64 + (jl ^ ((c >> 2) & 7))) * 4 + jq];
            s += fabs((double)xiv - (double)bv);
        }
        rs[(wv * 2 + t) * NCAND + cl] = s;
    }
    asm volatile("s_waitcnt lgkmcnt(0)" ::: "memory");

    if (cl < NCAND) {
        int rank = 0;
        #pragma unroll 4
        for (int o = 0; o < NCAND; ++o) {
            double so = rs[(wv * 2 + t) * NCAND + o];
            int    jo = candj[(wv * 2 + t) * NCAND + o];
            rank += (so < s || (so == s && jo < myj)) ? 1 : 0;
        }
        if (rank < K_SEL) {
            const int pwin = grp * 32 + wv * 2 + t;        // 0..255 in window
            const int gp   = win * 256 + pwin;
            feat[gp * 48 + rank] = (float)(1.0 - s * 0.03125);
            float dh = (float)((pwin >> 4) - (myj >> 4)) * (1.0f / 15.0f);
            float dw = (float)((pwin & 15) - (myj & 15)) * (1.0f / 15.0f);
            reinterpret_cast<float2*>(feat)[gp * 24 + 8 + rank] = make_float2(dh, dw);
        }
    }
}

__global__ __launch_bounds__(1024) void simtopk_kernel(
    const float* __restrict__ x,    // (64, 256, 32) fp32
    float* __restrict__ feat)       // (16384, 48)
{
    __shared__ __align__(16) float xsT[8192];          // 32 KB
    __shared__ int    candj[16 * 2 * NCAND];
    __shared__ double rs[16 * 2 * NCAND];

    const int tid = threadIdx.x;
    const int win = blockIdx.x >> 3;
    const int grp = blockIdx.x & 7;

    switch (grp >> 1) {                                 // comp is compile-time
        case 0: simtopk_body<0>(x, feat, xsT, candj, rs, win, grp, tid); break;
        case 1: simtopk_body<1>(x, feat, xsT, candj, rs, win, grp, tid); break;
        case 2: simtopk_body<2>(x, feat, xsT, candj, rs, win, grp, tid); break;
        default: simtopk_body<3>(x, feat, xsT, candj, rs, win, grp, tid); break;
    }
}

// ---------------------------------------------------------------------------
// pack_kernel (unchanged): weights -> split-bf16 hi/lo planes, B-fragment order
// idx = ((ks*N + n)*4 + kb)*8 + i  <->  W[ks*32+kb*8+i][n].
// ---------------------------------------------------------------------------
__global__ __launch_bounds__(256) void pack_kernel(
    const float* __restrict__ s0w, const float* __restrict__ s1w,
    const float* __restrict__ sow, const float* __restrict__ o0w,
    const float* __restrict__ o1w, const float* __restrict__ oow,
    short* __restrict__ wpack)
{
    int t = blockIdx.x * 256 + threadIdx.x;
    if (t >= 69632) return;
    int l, base;
    if      (t <  8192) { l = 0; base = 0;     }
    else if (t < 24576) { l = 1; base = 8192;  }
    else if (t < 32768) { l = 2; base = 24576; }
    else if (t < 45056) { l = 3; base = 32768; }
    else if (t < 61440) { l = 4; base = 45056; }
    else                { l = 5; base = 61440; }

    const float* W = (l == 0) ? s0w : (l == 1) ? s1w : (l == 2) ? sow
                   : (l == 3) ? o0w : (l == 4) ? o1w : oow;
    int N    = (l == 2 || l == 5) ? 64 : 128;
    int Kr   = (l == 0) ? 48 : (l == 3) ? 96 : 128;
    int woff = (l == 0) ? 0 : (l == 1) ? 16384 : (l == 2) ? 49152
             : (l == 3) ? 65536 : (l == 4) ? 90112 : 122880;
    int sz   = (l == 2 || l == 5) ? 8192 : (l == 3) ? 12288 : (l == 0) ? 8192 : 16384;

    int e = t - base;
    int i = e & 7, kb = (e >> 3) & 3, rem = e >> 5;
    int n = rem % N, ks = rem / N;
    int k = ks * 32 + kb * 8 + i;
    float v = (k < Kr) ? W[k * N + n] : 0.0f;
    short hi = f2bf_bits(v);
    float lo = v - bf2f_bits(hi);
    wpack[woff + e]      = hi;
    wpack[woff + sz + e] = f2bf_bits(lo);
}

// ---------------------------------------------------------------------------
// Kernel B (R10-proven, unchanged): FFN with bf16 hi/lo activation planes in
// LDS, consumed directly as MFMA A-fragments.  32 px/block, grid 512.
// ---------------------------------------------------------------------------
template<int K_STEPS, int N, bool RELU, bool TO_GLOBAL>
__device__ __forceinline__ void bf16_layer(
    const short* hiIn, const short* loIn, short* hiOut, short* loOut,
    float* gout, int pbase, const short* __restrict__ wpack, int woff, int sz,
    const float* __restrict__ bias, int wv, int lane, int out_col_off)
{
    if (N == 64 && wv >= 8) return;
    const int mt  = wv & 1;
    const int nt  = wv >> 1;
    const int m_a = mt * 16 + (lane & 15);
    const int kb  = lane >> 4;
    const int n   = nt * 16 + (lane & 15);

    f32x4 acc = (f32x4){0.f, 0.f, 0.f, 0.f};
    #pragma unroll
    for (int ks = 0; ks < K_STEPS; ++ks) {
        const int g   = ks * 4 + kb;
        const int off = m_a * 256 + ((g ^ (m_a & 7)) << 4);
        short8 ahi = *(const short8*)((const char*)hiIn + off);
        short8 alo = *(const short8*)((const char*)loIn + off);
        const int wi = woff + ((ks * N + n) * 4 + kb) * 8;
        short8 whi = *(const short8*)(wpack + wi);
        short8 wlo = *(const short8*)(wpack + wi + sz);
        acc = __builtin_amdgcn_mfma_f32_16x16x32_bf16(ahi, whi, acc, 0, 0, 0);
        acc = __builtin_amdgcn_mfma_f32_16x16x32_bf16(ahi, wlo, acc, 0, 0, 0);
        acc = __builtin_amdgcn_mfma_f32_16x16x32_bf16(alo, whi, acc, 0, 0, 0);
    }

    const float bv = bias[n];
    #pragma unroll
    for (int r = 0; r < 4; ++r) {
        float v = acc[r] + bv;
        if (RELU) v = fmaxf(v, 0.0f);
        const int pw = mt * 16 + (lane >> 4) * 4 + r;
        if (TO_GLOBAL) {
            gout[(size_t)(pbase + pw) * 64 + n] = v;
        } else {
            const int w   = out_col_off + n;
            const int off = pw * 256 + ((((w >> 3) ^ (pw & 7))) << 4) + (w & 7) * 2;
            short h = f2bf_bits(v);
            short l = f2bf_bits(v - bf2f_bits(h));
            *(short*)((char*)hiOut + off) = h;
            *(short*)((char*)loOut + off) = l;
        }
    }
}

__global__ __launch_bounds__(1024) void ffn_kernel(
    const float* __restrict__ x,     // (16384, 32)
    const float* __restrict__ feat,  // (16384, 48)
    const short* __restrict__ wpack,
    const float* __restrict__ s0b, const float* __restrict__ s1b,
    const float* __restrict__ sob, const float* __restrict__ o0b,
    const float* __restrict__ o1b, const float* __restrict__ oob,
    float* __restrict__ out)         // (16384, 64)
{
    __shared__ __align__(16) short hiA[32 * 128];   // 8 KB each
    __shared__ __align__(16) short loA[32 * 128];
    __shared__ __align__(16) short hiB[32 * 128];
    __shared__ __align__(16) short loB[32 * 128];

    const int tid   = threadIdx.x;
    const int lane  = tid & 63;
    const int wv    = tid >> 6;
    const int pbase = blockIdx.x * 32;

    // ---- stage feat (cols 0..47, split) + zero cols 48..63 into planes A ----
    if (tid < 384) {
        int p = tid / 12, c4 = tid - p * 12;
        f32x4 v = ((const f32x4*)feat)[(size_t)(pbase + p) * 12 + c4];
        short4v h4, l4;
        #pragma unroll
        for (int j = 0; j < 4; ++j) {
            short h = f2bf_bits(v[j]);
            h4[j] = h;
            l4[j] = f2bf_bits(v[j] - bf2f_bits(h));
        }
        int off = p * 256 + ((((c4 >> 1) ^ (p & 7))) << 4) + (c4 & 1) * 8;
        *(short4v*)((char*)hiA + off) = h4;
        *(short4v*)((char*)loA + off) = l4;
    } else if (tid < 512) {
        int t2 = tid - 384;
        int p = t2 & 31, sel = t2 >> 5;
        int g = 6 + (sel & 1);
        int off = p * 256 + ((g ^ (p & 7)) << 4);
        short8 z = (short8){0,0,0,0,0,0,0,0};
        if (sel >> 1) *(short8*)((char*)loA + off) = z;
        else          *(short8*)((char*)hiA + off) = z;
    }
    __syncthreads();

    // L1: 48(+pad) -> 128 relu   (A -> B)
    bf16_layer<2, 128, true, false>(hiA, loA, hiB, loB, nullptr, pbase,
                                    wpack, 0, 8192, s0b, wv, lane, 0);
    __syncthreads();
    // L2: 128 -> 128 relu  (B -> A)
    bf16_layer<4, 128, true, false>(hiB, loB, hiA, loA, nullptr, pbase,
                                    wpack, 16384, 16384, s1b, wv, lane, 0);
    __syncthreads();
    // L3: 128 -> 64 (sf) into B cols 32..95 ; stage x into B cols 0..31
    if (tid < 256) {
        int p = tid >> 3, c4 = tid & 7;
        f32x4 v = ((const f32x4*)x)[(size_t)(pbase + p) * 8 + c4];
        short4v h4, l4;
        #pragma unroll
        for (int j = 0; j < 4; ++j) {
            short h = f2bf_bits(v[j]);
            h4[j] = h;
            l4[j] = f2bf_bits(v[j] - bf2f_bits(h));
        }
        int off = p * 256 + ((((c4 >> 1) ^ (p & 7))) << 4) + (c4 & 1) * 8;
        *(short4v*)((char*)hiB + off) = h4;
        *(short4v*)((char*)loB + off) = l4;
    }
    bf16_layer<4, 64, false, false>(hiA, loA, hiB, loB, nullptr, pbase,
                                    wpack, 49152, 8192, sob, wv, lane, 32);
    __syncthreads();
    // L4: 96 -> 128 relu  (B -> A)
    bf16_layer<3, 128, true, false>(hiB, loB, hiA, loA, nullptr, pbase,
                                    wpack, 65536, 12288, o0b, wv, lane, 0);
    __syncthreads();
    // L5: 128 -> 128 relu  (A -> B)
    bf16_layer<4, 128, true, false>(hiA, loA, hiB, loB, nullptr, pbase,
                                    wpack, 90112, 16384, o1b, wv, lane, 0);
    __syncthreads();
    // L6: 128 -> 64 (+bias) -> out
    bf16_layer<4, 64, false, true>(hiB, loB, nullptr, nullptr, out, pbase,
                                   wpack, 122880, 8192, oob, wv, lane, 0);
}

extern "C" void kernel_launch(void* const* d_in, const int* in_sizes, int n_in,
                              void* d_out, int out_size, void* d_ws, size_t ws_size,
                              hipStream_t stream) {
    const float* x    = (const float*)d_in[0];
    const float* s0w  = (const float*)d_in[1];
    const float* s0b  = (const float*)d_in[2];
    const float* s1w  = (const float*)d_in[3];
    const float* s1b  = (const float*)d_in[4];
    const float* sow  = (const float*)d_in[5];
    const float* sob  = (const float*)d_in[6];
    const float* o0w  = (const float*)d_in[7];
    const float* o0b  = (const float*)d_in[8];
    const float* o1w  = (const float*)d_in[9];
    const float* o1b  = (const float*)d_in[10];
    const float* oow  = (const float*)d_in[11];
    const float* oob  = (const float*)d_in[12];

    short* wpack = (short*)d_ws;                      // 278528 B
    float* feat  = (float*)((char*)d_ws + 524288);    // 16384*48 fp32
    float* out   = (float*)d_out;

    pack_kernel<<<272, 256, 0, stream>>>(s0w, s1w, sow, o0w, o1w, oow, wpack);
    simtopk_kernel<<<512, 1024, 0, stream>>>(x, feat);
    ffn_kernel<<<512, 1024, 0, stream>>>(x, feat, wpack,
                                         s0b, s1b, sob, o0b, o1b, oob,
                                         out);
}